// Round 21
// baseline (207.218 us; speedup 1.0000x reference)
//
#include <hip/hip_runtime.h>
#include <math.h>

#define F_IN 165
#define HID 16
#define NPB 256         // nodes per bucket
#define NPB_BITS 8
#define MAXB 512        // padded bucket-array size (nbuck=391)
#define CHUNK 4096      // edges per chunk (cnt / binscatter block)
#define EPT 16          // CHUNK/256
#define SSTAGE 12288    // sortnode LDS staging capacity (avg bucket ~8192)

typedef int      ivec4 __attribute__((ext_vector_type(4)));
typedef unsigned uvec4 __attribute__((ext_vector_type(4)));
typedef float    fvec4 __attribute__((ext_vector_type(4)));
typedef float    fvec2 __attribute__((ext_vector_type(2)));

__device__ __forceinline__ int ntl_i(const int* p) {
    return __builtin_nontemporal_load(p);
}
__device__ __forceinline__ unsigned ntl_u(const unsigned* p) {
    return __builtin_nontemporal_load(p);
}
__device__ __forceinline__ int4 ntl_i4(const int4* p) {
    ivec4 v = __builtin_nontemporal_load((const ivec4*)p);
    return make_int4(v.x, v.y, v.z, v.w);
}
__device__ __forceinline__ uint4 ntl_u4(const uint4* p) {
    uvec4 v = __builtin_nontemporal_load((const uvec4*)p);
    return make_uint4(v.x, v.y, v.z, v.w);
}
__device__ __forceinline__ float4 ntl_f4(const float4* p) {
    fvec4 v = __builtin_nontemporal_load((const fvec4*)p);
    return make_float4(v.x, v.y, v.z, v.w);
}
__device__ __forceinline__ float2 ntl_f2(const float2* p) {
    fvec2 v = __builtin_nontemporal_load((const fvec2*)p);
    return make_float2(v.x, v.y);
}
__device__ __forceinline__ float ntl_f(const float* p) {
    return __builtin_nontemporal_load(p);
}

__device__ __forceinline__ unsigned pk_bf16(float lo, float hi) {
    unsigned a = __float_as_uint(lo), b = __float_as_uint(hi);
    a += 0x7FFF + ((a >> 16) & 1);       // RNE
    b += 0x7FFF + ((b >> 16) & 1);
    return (a >> 16) | (b & 0xFFFF0000u);
}
#define BF_LO(w) __uint_as_float((w) << 16)
#define BF_HI(w) __uint_as_float((w) & 0xFFFF0000u)

// ---- fused front: blocks [0,NBg) = gemm1 (unscaled h=x@W1, bf16);
//      blocks [NBg,..) = per-chunk bucket histogram (k_cnt) ----
#define FMA1(vv, kk)                                                   \
    {                                                                  \
        float4 w = *(const float4*)(ws + (kk) * HID + c4);             \
        acc.x = fmaf((vv), w.x, acc.x); acc.y = fmaf((vv), w.y, acc.y);\
        acc.z = fmaf((vv), w.z, acc.z); acc.w = fmaf((vv), w.w, acc.w);\
    }

__global__ __launch_bounds__(256) void k_front(const float* __restrict__ x,
                                               const float* __restrict__ W1,
                                               unsigned* __restrict__ g1, int N,
                                               const int* __restrict__ dst,
                                               int* __restrict__ cbM, int E,
                                               int NBg) {
    int t = threadIdx.x;
    if ((int)blockIdx.x >= NBg) {
        // ---------- cnt path ----------
        __shared__ int h[MAXB];
        int blk = blockIdx.x - NBg;
        for (int i = t; i < MAXB; i += 256) h[i] = 0;
        __syncthreads();
        int e0 = blk * CHUNK;
        int n = min(CHUNK, E - e0);
        if (n == CHUNK) {
            const int4* d4 = (const int4*)(dst + e0);
#pragma unroll
            for (int u = 0; u < 4; ++u) {
                int4 v = ntl_i4(&d4[u * 256 + t]);
                atomicAdd(&h[v.x >> NPB_BITS], 1);
                atomicAdd(&h[v.y >> NPB_BITS], 1);
                atomicAdd(&h[v.z >> NPB_BITS], 1);
                atomicAdd(&h[v.w >> NPB_BITS], 1);
            }
        } else {
            for (int k = t; k < n; k += 256)
                atomicAdd(&h[ntl_i(&dst[e0 + k]) >> NPB_BITS], 1);
        }
        __syncthreads();
        for (int i = t; i < MAXB; i += 256)
            cbM[blk * MAXB + i] = h[i];
        return;
    }
    // ---------- gemm path (round-12 form, unscaled, nt x loads) ----------
    __shared__ float ws[F_IN * HID];   // 10.5 KB
    {
        const float4* w4 = (const float4*)W1;
        float4* s4 = (float4*)ws;
#pragma unroll
        for (int u = 0; u < 3; ++u) {
            int i = t + u * 256;
            if (i < (F_IN * HID) / 4) s4[i] = w4[i];
        }
    }
    __syncthreads();
    int gid = blockIdx.x * 256 + t;
    int row = gid >> 2;
    int c4 = (gid & 3) << 2;
    if (row >= N) return;
    const float* xr = x + (long long)row * F_IN;
    float4 acc = make_float4(0.f, 0.f, 0.f, 0.f);

    int p = (4 - (row & 3)) & 3;   // dwords to 16B boundary
    for (int k = 0; k < p; ++k) { float v = ntl_f(&xr[k]); FMA1(v, k); }

    const float4* xr4 = (const float4*)(xr + p);
    int n4 = (F_IN - p) >> 2;      // 40 or 41
    int q = 0;
    for (; q + 4 <= n4; q += 4) {
        float4 v0 = ntl_f4(&xr4[q]),     v1 = ntl_f4(&xr4[q + 1]);
        float4 v2 = ntl_f4(&xr4[q + 2]), v3 = ntl_f4(&xr4[q + 3]);
        int kb = p + q * 4;
        FMA1(v0.x, kb + 0)  FMA1(v0.y, kb + 1)  FMA1(v0.z, kb + 2)  FMA1(v0.w, kb + 3)
        FMA1(v1.x, kb + 4)  FMA1(v1.y, kb + 5)  FMA1(v1.z, kb + 6)  FMA1(v1.w, kb + 7)
        FMA1(v2.x, kb + 8)  FMA1(v2.y, kb + 9)  FMA1(v2.z, kb + 10) FMA1(v2.w, kb + 11)
        FMA1(v3.x, kb + 12) FMA1(v3.y, kb + 13) FMA1(v3.z, kb + 14) FMA1(v3.w, kb + 15)
    }
    for (; q < n4; ++q) {
        float4 v = ntl_f4(&xr4[q]);
        int kb = p + q * 4;
        FMA1(v.x, kb) FMA1(v.y, kb + 1) FMA1(v.z, kb + 2) FMA1(v.w, kb + 3)
    }
    for (int k = p + n4 * 4; k < F_IN; ++k) { float v = ntl_f(&xr[k]); FMA1(v, k); }

    uint2 o = make_uint2(pk_bf16(acc.x, acc.y), pk_bf16(acc.z, acc.w));
    *(uint2*)(g1 + (long long)row * 8 + (gid & 3) * 2) = o;
}

// ---- per-bucket column scan (in place): cbM[c][b] -> excl prefix; btot[b] ----
__global__ __launch_bounds__(256) void k_colscan(int* __restrict__ cbM,
                                                 int* __restrict__ btot, int NB) {
    __shared__ int ps[256];
    int b = blockIdx.x, t = threadIdx.x;
    int i0 = t * 4;
    int v[4];
    int s = 0;
#pragma unroll
    for (int u = 0; u < 4; ++u) {
        int c = i0 + u;
        v[u] = (c < NB) ? cbM[c * MAXB + b] : 0;
        s += v[u];
    }
    ps[t] = s;
    __syncthreads();
    for (int off = 1; off < 256; off <<= 1) {
        int a = (t >= off) ? ps[t - off] : 0;
        __syncthreads();
        ps[t] += a;
        __syncthreads();
    }
    int run = ps[t] - s;
#pragma unroll
    for (int u = 0; u < 4; ++u) {
        int c = i0 + u;
        if (c < NB) cbM[c * MAXB + b] = run;
        run += v[u];
    }
    if (t == 255) btot[b] = ps[255];
}

// ---- counting-sort edges into bucket-major order, packed (src<<8)|dstlow ----
__global__ __launch_bounds__(256) void k_binscatter(const int* __restrict__ src,
                                                    const int* __restrict__ dst,
                                                    const int* __restrict__ cbM,
                                                    const int* __restrict__ btot,
                                                    unsigned* __restrict__ sedge,
                                                    int E, int nbuck) {
    __shared__ int hist[MAXB];      // counts, then reused as local bofs
    __shared__ int lofs[MAXB];
    __shared__ int dlt[MAXB];
    __shared__ int ps[256];
    __shared__ uint2 stg[CHUNK];
    int t = threadIdx.x;
    int me = blockIdx.x;
    int e0 = me * CHUNK;
    int n = min(CHUNK, E - e0);

    int d[EPT], sv[EPT], rk[EPT];
    if (n == CHUNK) {
        const int4* dd = (const int4*)(dst + e0);
        const int4* ss = (const int4*)(src + e0);
#pragma unroll
        for (int u = 0; u < 4; ++u) {
            int4 dv = ntl_i4(&dd[u * 256 + t]);
            int4 vv = ntl_i4(&ss[u * 256 + t]);
            d[u * 4 + 0] = dv.x; d[u * 4 + 1] = dv.y;
            d[u * 4 + 2] = dv.z; d[u * 4 + 3] = dv.w;
            sv[u * 4 + 0] = vv.x; sv[u * 4 + 1] = vv.y;
            sv[u * 4 + 2] = vv.z; sv[u * 4 + 3] = vv.w;
        }
    } else {
#pragma unroll
        for (int u = 0; u < EPT; ++u) {
            int k = t + u * 256;
            d[u]  = (k < n) ? ntl_i(&dst[e0 + k]) : -1;
            sv[u] = (k < n) ? ntl_i(&src[e0 + k]) : 0;
        }
    }
    for (int i = t; i < MAXB; i += 256) hist[i] = 0;
    __syncthreads();
#pragma unroll
    for (int u = 0; u < EPT; ++u)
        if (d[u] >= 0) rk[u] = atomicAdd(&hist[d[u] >> NPB_BITS], 1);
    __syncthreads();

    // scan 1: chunk histogram -> lofs
    int base = t * 2;
    int h0 = hist[base], h1 = hist[base + 1];
    int s = h0 + h1;
    ps[t] = s;
    __syncthreads();
    for (int off = 1; off < 256; off <<= 1) {
        int a = (t >= off) ? ps[t - off] : 0;
        __syncthreads();
        ps[t] += a;
        __syncthreads();
    }
    int excl = ps[t] - s;
    lofs[base] = excl;
    lofs[base + 1] = excl + h0;

    // scan 2: btot -> local bofs (reuse hist)
    int c0v = (base < nbuck) ? btot[base] : 0;
    int c1v = (base + 1 < nbuck) ? btot[base + 1] : 0;
    int s2 = c0v + c1v;
    __syncthreads();
    ps[t] = s2;
    __syncthreads();
    for (int off = 1; off < 256; off <<= 1) {
        int a = (t >= off) ? ps[t - off] : 0;
        __syncthreads();
        ps[t] += a;
        __syncthreads();
    }
    int ex2 = ps[t] - s2;
    hist[base] = ex2;
    hist[base + 1] = ex2 + c0v;
    __syncthreads();
    for (int i = t; i < nbuck; i += 256)
        dlt[i] = hist[i] + cbM[me * MAXB + i] - lofs[i];
    __syncthreads();

    // place into bucket-major staging at r = lofs[b] + rank; addr fused in .y
#pragma unroll
    for (int u = 0; u < EPT; ++u) {
        if (d[u] < 0) continue;
        int b = d[u] >> NPB_BITS;
        int r = lofs[b] + rk[u];
        stg[r] = make_uint2(((unsigned)sv[u] << NPB_BITS) | (unsigned)(d[u] & (NPB - 1)),
                            (unsigned)(dlt[b] + r));
    }
    __syncthreads();

    // write-out: stride-1 LDS read pair + store (depth-1 chain)
    for (int r = t; r < n; r += 256) {
        uint2 v = stg[r];
        sedge[v.y] = v.x;
    }
}

// ---- within-bucket: node histogram -> rowptr + dinv + sorted csr,
//      AND scale this bucket's g1 rows by dinv (in place, bf16) ----
__global__ __launch_bounds__(256) void k_sortnode(const int* __restrict__ btot,
                                                  const unsigned* __restrict__ sedge,
                                                  int* __restrict__ csr,
                                                  int* __restrict__ rowptr,
                                                  float* __restrict__ dinv,
                                                  unsigned* __restrict__ g1,
                                                  int nbuck, int N) {
    __shared__ int hist[256];
    __shared__ int ps[256];
    __shared__ int lcur[256];
    __shared__ int stage[SSTAGE];
    __shared__ int sbase;
    int b = blockIdx.x, t = threadIdx.x;

    // exclusive prefix of btot up to b
    int t2 = 2 * t;
    int c0v = (t2 < nbuck) ? btot[t2] : 0;
    int c1v = (t2 + 1 < nbuck) ? btot[t2 + 1] : 0;
    int ssum = c0v + c1v;
    ps[t] = ssum;
    __syncthreads();
    for (int off = 1; off < 256; off <<= 1) {
        int a = (t >= off) ? ps[t - off] : 0;
        __syncthreads();
        ps[t] += a;
        __syncthreads();
    }
    if (t == (b >> 1)) sbase = (ps[t] - ssum) + ((b & 1) ? c0v : 0);
    __syncthreads();
    int base = sbase;
    int n = btot[b];
    if (b == nbuck - 1 && t == 0) rowptr[N] = base + n;

    hist[t] = 0;
    __syncthreads();
    for (int k = t; k < n; k += 256)
        atomicAdd(&hist[ntl_u(&sedge[base + k]) & (NPB - 1)], 1);
    __syncthreads();
    int c = hist[t];
    ps[t] = c;
    __syncthreads();
    for (int off = 1; off < 256; off <<= 1) {
        int a = (t >= off) ? ps[t - off] : 0;
        __syncthreads();
        ps[t] += a;
        __syncthreads();
    }
    int excl = ps[t] - c;
    int node = b * NPB + t;
    if (node < N) {
        rowptr[node] = base + excl;
        float di = rsqrtf((float)c + 1.0f);
        dinv[node] = di;
        // scale this node's g1 row (8 words = 16 bf16) by di, in place
        uint4* gr = (uint4*)(g1 + (long long)node * 8);
        uint4 a = gr[0], bb = gr[1];
        a.x = pk_bf16(BF_LO(a.x) * di, BF_HI(a.x) * di);
        a.y = pk_bf16(BF_LO(a.y) * di, BF_HI(a.y) * di);
        a.z = pk_bf16(BF_LO(a.z) * di, BF_HI(a.z) * di);
        a.w = pk_bf16(BF_LO(a.w) * di, BF_HI(a.w) * di);
        bb.x = pk_bf16(BF_LO(bb.x) * di, BF_HI(bb.x) * di);
        bb.y = pk_bf16(BF_LO(bb.y) * di, BF_HI(bb.y) * di);
        bb.z = pk_bf16(BF_LO(bb.z) * di, BF_HI(bb.z) * di);
        bb.w = pk_bf16(BF_LO(bb.w) * di, BF_HI(bb.w) * di);
        gr[0] = a; gr[1] = bb;
    }
    lcur[t] = excl;
    __syncthreads();
    bool staged = (n <= SSTAGE);
    for (int k = t; k < n; k += 256) {
        unsigned p = ntl_u(&sedge[base + k]);
        int dd = p & (NPB - 1);
        int pos = atomicAdd(&lcur[dd], 1);
        int svv = (int)(p >> NPB_BITS);
        if (staged) stage[pos] = svv;
        else        csr[base + pos] = svv;
    }
    __syncthreads();
    if (staged) {
        for (int k = t; k < n; k += 256) csr[base + k] = stage[k];
    }
}

// ---- layer-1 CSR gather: 8 lanes/node = (feature-half j, edge-quarter part) ----
#define ACC8(U)                                                         \
    l0 += BF_LO(U.x); h0 += BF_HI(U.x); l1 += BF_LO(U.y); h1 += BF_HI(U.y); \
    l2 += BF_LO(U.z); h2 += BF_HI(U.z); l3 += BF_LO(U.w); h3 += BF_HI(U.w);

__global__ __launch_bounds__(256) void k_agg1(const int* __restrict__ rowptr,
                                              const int* __restrict__ csr,
                                              const unsigned* __restrict__ g1,
                                              const float* __restrict__ dinv,
                                              const float* __restrict__ b1,
                                              const float* __restrict__ W2,
                                              float* __restrict__ g2, int N) {
    int gid = blockIdx.x * 256 + threadIdx.x;
    int i = gid >> 3;
    int j = gid & 1;                       // feature half (8 feats)
    int part = (gid >> 1) & 3;             // edge quarter
    if (i >= N) return;
    int e0 = rowptr[i], e1 = rowptr[i + 1];
    int len = e1 - e0;
    int qs = e0 + ((len * part) >> 2);
    int qe = e0 + ((len * (part + 1)) >> 2);
    const uint4* G = (const uint4*)g1;     // row i half j at G[i*2+j]
    float l0 = 0.f, h0 = 0.f, l1 = 0.f, h1 = 0.f;
    float l2 = 0.f, h2 = 0.f, l3 = 0.f, h3 = 0.f;
    if (part == 0) { uint4 w0 = ntl_u4(&G[i * 2 + j]); ACC8(w0) }   // self-loop once
    int e = qs;
    int p = (4 - (e & 3)) & 3;
    p = min(p, qe - e);
    for (int k = 0; k < p; ++k, ++e) { uint4 u = ntl_u4(&G[ntl_i(&csr[e]) * 2 + j]); ACC8(u) }
    const int4* c4 = (const int4*)(csr + e);
    int nq = (qe - e) >> 2;
    int q = 0;
    for (; q + 2 <= nq; q += 2) {
        int4 a = ntl_i4(&c4[q]), b = ntl_i4(&c4[q + 1]);
        uint4 u0 = ntl_u4(&G[a.x * 2 + j]), u1 = ntl_u4(&G[a.y * 2 + j]);
        uint4 u2 = ntl_u4(&G[a.z * 2 + j]), u3 = ntl_u4(&G[a.w * 2 + j]);
        uint4 u4 = ntl_u4(&G[b.x * 2 + j]), u5 = ntl_u4(&G[b.y * 2 + j]);
        uint4 u6 = ntl_u4(&G[b.z * 2 + j]), u7 = ntl_u4(&G[b.w * 2 + j]);
        ACC8(u0) ACC8(u1) ACC8(u2) ACC8(u3)
        ACC8(u4) ACC8(u5) ACC8(u6) ACC8(u7)
    }
    for (; q < nq; ++q) {
        int4 a = ntl_i4(&c4[q]);
        uint4 u0 = ntl_u4(&G[a.x * 2 + j]), u1 = ntl_u4(&G[a.y * 2 + j]);
        uint4 u2 = ntl_u4(&G[a.z * 2 + j]), u3 = ntl_u4(&G[a.w * 2 + j]);
        ACC8(u0) ACC8(u1) ACC8(u2) ACC8(u3)
    }
    e += nq * 4;
    for (; e < qe; ++e) { uint4 u = ntl_u4(&G[ntl_i(&csr[e]) * 2 + j]); ACC8(u) }

    // reduce the 8 partial accums across parts (gid bits 1,2)
#pragma unroll
    for (int off = 2; off <= 4; off <<= 1) {
        l0 += __shfl_xor(l0, off, 8); h0 += __shfl_xor(h0, off, 8);
        l1 += __shfl_xor(l1, off, 8); h1 += __shfl_xor(h1, off, 8);
        l2 += __shfl_xor(l2, off, 8); h2 += __shfl_xor(h2, off, 8);
        l3 += __shfl_xor(l3, off, 8); h3 += __shfl_xor(h3, off, 8);
    }
    if (part != 0) return;
    float di = dinv[i];
    int fb = j * 8;
    float c0 = 0.f, c1 = 0.f;
#define EPI(val, fi)                                                     \
    {                                                                    \
        float v = fmaf((val), di, b1[fb + (fi)]);                        \
        v = v > 0.f ? v : 0.f;                                           \
        float2 w = ((const float2*)W2)[fb + (fi)];                       \
        c0 = fmaf(v, w.x, c0);                                           \
        c1 = fmaf(v, w.y, c1);                                           \
    }
    EPI(l0, 0) EPI(h0, 1) EPI(l1, 2) EPI(h1, 3)
    EPI(l2, 4) EPI(h2, 5) EPI(l3, 6) EPI(h3, 7)
    c0 += __shfl_xor(c0, 1, 2);
    c1 += __shfl_xor(c1, 1, 2);
    if (j == 0) ((float2*)g2)[i] = make_float2(c0 * di, c1 * di);
}

// ---- layer-2 CSR gather + fused log_softmax -> out (4 lanes/node) ----
__global__ __launch_bounds__(256) void k_agg2(const int* __restrict__ rowptr,
                                              const int* __restrict__ csr,
                                              const float* __restrict__ g2,
                                              const float* __restrict__ dinv,
                                              const float* __restrict__ b2,
                                              float* __restrict__ out, int N) {
    int gid = blockIdx.x * 256 + threadIdx.x;
    int i = gid >> 2;
    int l = gid & 3;
    if (i >= N) return;
    int e0 = rowptr[i], e1 = rowptr[i + 1];
    const float2* G2 = (const float2*)g2;
    float a0 = 0.f, a1 = 0.f;
    int e = e0 + l;
    for (; e + 4 < e1; e += 8) {
        int s0 = ntl_i(&csr[e]), s1 = ntl_i(&csr[e + 4]);
        float2 u = ntl_f2(&G2[s0]);
        float2 w = ntl_f2(&G2[s1]);
        a0 += u.x + w.x;
        a1 += u.y + w.y;
    }
    for (; e < e1; e += 4) {
        int s = ntl_i(&csr[e]);
        float2 u = ntl_f2(&G2[s]);
        a0 += u.x;
        a1 += u.y;
    }
    a0 += __shfl_xor(a0, 1, 4); a0 += __shfl_xor(a0, 2, 4);
    a1 += __shfl_xor(a1, 1, 4); a1 += __shfl_xor(a1, 2, 4);
    if (l == 0) {
        float2 self = G2[i];
        float di = dinv[i];
        float A = fmaf(a0 + self.x, di, b2[0]);
        float B = fmaf(a1 + self.y, di, b2[1]);
        float m = fmaxf(A, B);
        float lse = m + logf(expf(A - m) + expf(B - m));
        ((float2*)out)[i] = make_float2(A - lse, B - lse);
    }
}

extern "C" void kernel_launch(void* const* d_in, const int* in_sizes, int n_in,
                              void* d_out, int out_size, void* d_ws, size_t ws_size,
                              hipStream_t stream) {
    const float* x  = (const float*)d_in[0];
    const int*   ei = (const int*)d_in[1];
    const float* W1 = (const float*)d_in[2];
    const float* b1 = (const float*)d_in[3];
    const float* W2 = (const float*)d_in[4];
    const float* b2 = (const float*)d_in[5];
    float* out = (float*)d_out;

    int N = in_sizes[0] / F_IN;
    int E = in_sizes[1] / 2;
    const int* src = ei;
    const int* dst = ei + E;
    int nbuck = (N + NPB - 1) >> NPB_BITS;
    int NB = (E + CHUNK - 1) / CHUNK;
    int NBg = (N * 4 + 255) / 256;

    int* cbM      = (int*)d_ws;                     // NB*MAXB (counts -> excl offsets)
    int* btot     = cbM + (long long)NB * MAXB;     // MAXB
    int* rowptr   = btot + MAXB;                    // N+1
    unsigned* sedge = (unsigned*)(rowptr + N + 1);  // E
    int* csr      = (int*)(sedge + E);              // E
    float* dinv   = (float*)(csr + E);              // N
    unsigned* g1  = (unsigned*)(dinv + N);          // 8N (bf16 rows)
    float* g2     = (float*)(g1 + (long long)8 * N);// 2N

    k_front<<<NBg + NB, 256, 0, stream>>>(x, W1, g1, N, dst, cbM, E, NBg);
    k_colscan<<<nbuck, 256, 0, stream>>>(cbM, btot, NB);
    k_binscatter<<<NB, 256, 0, stream>>>(src, dst, cbM, btot, sedge, E, nbuck);
    k_sortnode<<<nbuck, 256, 0, stream>>>(btot, sedge, csr, rowptr, dinv, g1, nbuck, N);

    k_agg1<<<((long long)N * 8 + 255) / 256, 256, 0, stream>>>(rowptr, csr, g1, dinv, b1, W2, g2, N);
    k_agg2<<<(N * 4 + 255) / 256, 256, 0, stream>>>(rowptr, csr, g2, dinv, b2, out, N);
}

// Round 22
// 118.869 us; speedup vs baseline: 1.7432x; 1.7432x over previous
//
#include <hip/hip_runtime.h>
#include <math.h>

#define F_IN 165
#define HID 16
#define NPB 256         // nodes per bucket
#define NPB_BITS 8
#define MAXB 512        // padded bucket-array size (nbuck=391)
#define CHUNK 4096      // edges per chunk (cnt / binscatter block)
#define EPT 16          // CHUNK/256
#define SSTAGE 12288    // sortnode LDS staging capacity (avg bucket ~8192)

__device__ __forceinline__ unsigned pk_bf16(float lo, float hi) {
    unsigned a = __float_as_uint(lo), b = __float_as_uint(hi);
    a += 0x7FFF + ((a >> 16) & 1);       // RNE
    b += 0x7FFF + ((b >> 16) & 1);
    return (a >> 16) | (b & 0xFFFF0000u);
}
#define BF_LO(w) __uint_as_float((w) << 16)
#define BF_HI(w) __uint_as_float((w) & 0xFFFF0000u)

// ---- fused front: blocks [0,NBg) = gemm1 (unscaled h=x@W1, bf16);
//      blocks [NBg,..) = per-chunk bucket histogram (k_cnt) ----
#define FMA1(vv, kk)                                                   \
    {                                                                  \
        float4 w = *(const float4*)(ws + (kk) * HID + c4);             \
        acc.x = fmaf((vv), w.x, acc.x); acc.y = fmaf((vv), w.y, acc.y);\
        acc.z = fmaf((vv), w.z, acc.z); acc.w = fmaf((vv), w.w, acc.w);\
    }

__global__ __launch_bounds__(256) void k_front(const float* __restrict__ x,
                                               const float* __restrict__ W1,
                                               unsigned* __restrict__ g1, int N,
                                               const int* __restrict__ dst,
                                               int* __restrict__ cbM, int E,
                                               int NBg) {
    int t = threadIdx.x;
    if ((int)blockIdx.x >= NBg) {
        // ---------- cnt path ----------
        __shared__ int h[MAXB];
        int blk = blockIdx.x - NBg;
        for (int i = t; i < MAXB; i += 256) h[i] = 0;
        __syncthreads();
        int e0 = blk * CHUNK;
        int n = min(CHUNK, E - e0);
        if (n == CHUNK) {
            const int4* d4 = (const int4*)(dst + e0);
#pragma unroll
            for (int u = 0; u < 4; ++u) {
                int4 v = d4[u * 256 + t];
                atomicAdd(&h[v.x >> NPB_BITS], 1);
                atomicAdd(&h[v.y >> NPB_BITS], 1);
                atomicAdd(&h[v.z >> NPB_BITS], 1);
                atomicAdd(&h[v.w >> NPB_BITS], 1);
            }
        } else {
            for (int k = t; k < n; k += 256)
                atomicAdd(&h[dst[e0 + k] >> NPB_BITS], 1);
        }
        __syncthreads();
        for (int i = t; i < MAXB; i += 256)
            cbM[blk * MAXB + i] = h[i];
        return;
    }
    // ---------- gemm path (round-12 form, unscaled) ----------
    __shared__ float ws[F_IN * HID];   // 10.5 KB
    {
        const float4* w4 = (const float4*)W1;
        float4* s4 = (float4*)ws;
#pragma unroll
        for (int u = 0; u < 3; ++u) {
            int i = t + u * 256;
            if (i < (F_IN * HID) / 4) s4[i] = w4[i];
        }
    }
    __syncthreads();
    int gid = blockIdx.x * 256 + t;
    int row = gid >> 2;
    int c4 = (gid & 3) << 2;
    if (row >= N) return;
    const float* xr = x + (long long)row * F_IN;
    float4 acc = make_float4(0.f, 0.f, 0.f, 0.f);

    int p = (4 - (row & 3)) & 3;   // dwords to 16B boundary
    for (int k = 0; k < p; ++k) { float v = xr[k]; FMA1(v, k); }

    const float4* xr4 = (const float4*)(xr + p);
    int n4 = (F_IN - p) >> 2;      // 40 or 41
    int q = 0;
    for (; q + 4 <= n4; q += 4) {
        float4 v0 = xr4[q], v1 = xr4[q + 1], v2 = xr4[q + 2], v3 = xr4[q + 3];
        int kb = p + q * 4;
        FMA1(v0.x, kb + 0)  FMA1(v0.y, kb + 1)  FMA1(v0.z, kb + 2)  FMA1(v0.w, kb + 3)
        FMA1(v1.x, kb + 4)  FMA1(v1.y, kb + 5)  FMA1(v1.z, kb + 6)  FMA1(v1.w, kb + 7)
        FMA1(v2.x, kb + 8)  FMA1(v2.y, kb + 9)  FMA1(v2.z, kb + 10) FMA1(v2.w, kb + 11)
        FMA1(v3.x, kb + 12) FMA1(v3.y, kb + 13) FMA1(v3.z, kb + 14) FMA1(v3.w, kb + 15)
    }
    for (; q < n4; ++q) {
        float4 v = xr4[q];
        int kb = p + q * 4;
        FMA1(v.x, kb) FMA1(v.y, kb + 1) FMA1(v.z, kb + 2) FMA1(v.w, kb + 3)
    }
    for (int k = p + n4 * 4; k < F_IN; ++k) { float v = xr[k]; FMA1(v, k); }

    uint2 o = make_uint2(pk_bf16(acc.x, acc.y), pk_bf16(acc.z, acc.w));
    *(uint2*)(g1 + (long long)row * 8 + (gid & 3) * 2) = o;
}

// ---- per-bucket column scan (in place): cbM[c][b] -> excl prefix; btot[b] ----
__global__ __launch_bounds__(256) void k_colscan(int* __restrict__ cbM,
                                                 int* __restrict__ btot, int NB) {
    __shared__ int ps[256];
    int b = blockIdx.x, t = threadIdx.x;
    int i0 = t * 4;
    int v[4];
    int s = 0;
#pragma unroll
    for (int u = 0; u < 4; ++u) {
        int c = i0 + u;
        v[u] = (c < NB) ? cbM[c * MAXB + b] : 0;
        s += v[u];
    }
    ps[t] = s;
    __syncthreads();
    for (int off = 1; off < 256; off <<= 1) {
        int a = (t >= off) ? ps[t - off] : 0;
        __syncthreads();
        ps[t] += a;
        __syncthreads();
    }
    int run = ps[t] - s;
#pragma unroll
    for (int u = 0; u < 4; ++u) {
        int c = i0 + u;
        if (c < NB) cbM[c * MAXB + b] = run;
        run += v[u];
    }
    if (t == 255) btot[b] = ps[255];
}

// ---- counting-sort edges into bucket-major order, packed (src<<8)|dstlow ----
__global__ __launch_bounds__(256) void k_binscatter(const int* __restrict__ src,
                                                    const int* __restrict__ dst,
                                                    const int* __restrict__ cbM,
                                                    const int* __restrict__ btot,
                                                    unsigned* __restrict__ sedge,
                                                    int E, int nbuck) {
    __shared__ int hist[MAXB];      // counts, then reused as local bofs
    __shared__ int lofs[MAXB];
    __shared__ int dlt[MAXB];
    __shared__ int ps[256];
    __shared__ uint2 stg[CHUNK];
    int t = threadIdx.x;
    int me = blockIdx.x;
    int e0 = me * CHUNK;
    int n = min(CHUNK, E - e0);

    int d[EPT], sv[EPT], rk[EPT];
    if (n == CHUNK) {
        const int4* dd = (const int4*)(dst + e0);
        const int4* ss = (const int4*)(src + e0);
#pragma unroll
        for (int u = 0; u < 4; ++u) {
            int4 dv = dd[u * 256 + t];
            int4 vv = ss[u * 256 + t];
            d[u * 4 + 0] = dv.x; d[u * 4 + 1] = dv.y;
            d[u * 4 + 2] = dv.z; d[u * 4 + 3] = dv.w;
            sv[u * 4 + 0] = vv.x; sv[u * 4 + 1] = vv.y;
            sv[u * 4 + 2] = vv.z; sv[u * 4 + 3] = vv.w;
        }
    } else {
#pragma unroll
        for (int u = 0; u < EPT; ++u) {
            int k = t + u * 256;
            d[u]  = (k < n) ? dst[e0 + k] : -1;
            sv[u] = (k < n) ? src[e0 + k] : 0;
        }
    }
    for (int i = t; i < MAXB; i += 256) hist[i] = 0;
    __syncthreads();
#pragma unroll
    for (int u = 0; u < EPT; ++u)
        if (d[u] >= 0) rk[u] = atomicAdd(&hist[d[u] >> NPB_BITS], 1);
    __syncthreads();

    // scan 1: chunk histogram -> lofs
    int base = t * 2;
    int h0 = hist[base], h1 = hist[base + 1];
    int s = h0 + h1;
    ps[t] = s;
    __syncthreads();
    for (int off = 1; off < 256; off <<= 1) {
        int a = (t >= off) ? ps[t - off] : 0;
        __syncthreads();
        ps[t] += a;
        __syncthreads();
    }
    int excl = ps[t] - s;
    lofs[base] = excl;
    lofs[base + 1] = excl + h0;

    // scan 2: btot -> local bofs (reuse hist)
    int c0v = (base < nbuck) ? btot[base] : 0;
    int c1v = (base + 1 < nbuck) ? btot[base + 1] : 0;
    int s2 = c0v + c1v;
    __syncthreads();
    ps[t] = s2;
    __syncthreads();
    for (int off = 1; off < 256; off <<= 1) {
        int a = (t >= off) ? ps[t - off] : 0;
        __syncthreads();
        ps[t] += a;
        __syncthreads();
    }
    int ex2 = ps[t] - s2;
    hist[base] = ex2;
    hist[base + 1] = ex2 + c0v;
    __syncthreads();
    for (int i = t; i < nbuck; i += 256)
        dlt[i] = hist[i] + cbM[me * MAXB + i] - lofs[i];
    __syncthreads();

    // place into bucket-major staging at r = lofs[b] + rank; addr fused in .y
#pragma unroll
    for (int u = 0; u < EPT; ++u) {
        if (d[u] < 0) continue;
        int b = d[u] >> NPB_BITS;
        int r = lofs[b] + rk[u];
        stg[r] = make_uint2(((unsigned)sv[u] << NPB_BITS) | (unsigned)(d[u] & (NPB - 1)),
                            (unsigned)(dlt[b] + r));
    }
    __syncthreads();

    // write-out: stride-1 LDS read pair + store (depth-1 chain)
    for (int r = t; r < n; r += 256) {
        uint2 v = stg[r];
        sedge[v.y] = v.x;
    }
}

// ---- within-bucket: node histogram -> rowptr + dinv + sorted csr,
//      AND scale this bucket's g1 rows by dinv (in place, bf16) ----
__global__ __launch_bounds__(256) void k_sortnode(const int* __restrict__ btot,
                                                  const unsigned* __restrict__ sedge,
                                                  int* __restrict__ csr,
                                                  int* __restrict__ rowptr,
                                                  float* __restrict__ dinv,
                                                  unsigned* __restrict__ g1,
                                                  int nbuck, int N) {
    __shared__ int hist[256];
    __shared__ int ps[256];
    __shared__ int lcur[256];
    __shared__ int stage[SSTAGE];
    __shared__ int sbase;
    int b = blockIdx.x, t = threadIdx.x;

    // exclusive prefix of btot up to b
    int t2 = 2 * t;
    int c0v = (t2 < nbuck) ? btot[t2] : 0;
    int c1v = (t2 + 1 < nbuck) ? btot[t2 + 1] : 0;
    int ssum = c0v + c1v;
    ps[t] = ssum;
    __syncthreads();
    for (int off = 1; off < 256; off <<= 1) {
        int a = (t >= off) ? ps[t - off] : 0;
        __syncthreads();
        ps[t] += a;
        __syncthreads();
    }
    if (t == (b >> 1)) sbase = (ps[t] - ssum) + ((b & 1) ? c0v : 0);
    __syncthreads();
    int base = sbase;
    int n = btot[b];
    if (b == nbuck - 1 && t == 0) rowptr[N] = base + n;

    hist[t] = 0;
    __syncthreads();
    for (int k = t; k < n; k += 256)
        atomicAdd(&hist[sedge[base + k] & (NPB - 1)], 1);
    __syncthreads();
    int c = hist[t];
    ps[t] = c;
    __syncthreads();
    for (int off = 1; off < 256; off <<= 1) {
        int a = (t >= off) ? ps[t - off] : 0;
        __syncthreads();
        ps[t] += a;
        __syncthreads();
    }
    int excl = ps[t] - c;
    int node = b * NPB + t;
    if (node < N) {
        rowptr[node] = base + excl;
        float di = rsqrtf((float)c + 1.0f);
        dinv[node] = di;
        // scale this node's g1 row (8 words = 16 bf16) by di, in place
        uint4* gr = (uint4*)(g1 + (long long)node * 8);
        uint4 a = gr[0], bb = gr[1];
        a.x = pk_bf16(BF_LO(a.x) * di, BF_HI(a.x) * di);
        a.y = pk_bf16(BF_LO(a.y) * di, BF_HI(a.y) * di);
        a.z = pk_bf16(BF_LO(a.z) * di, BF_HI(a.z) * di);
        a.w = pk_bf16(BF_LO(a.w) * di, BF_HI(a.w) * di);
        bb.x = pk_bf16(BF_LO(bb.x) * di, BF_HI(bb.x) * di);
        bb.y = pk_bf16(BF_LO(bb.y) * di, BF_HI(bb.y) * di);
        bb.z = pk_bf16(BF_LO(bb.z) * di, BF_HI(bb.z) * di);
        bb.w = pk_bf16(BF_LO(bb.w) * di, BF_HI(bb.w) * di);
        gr[0] = a; gr[1] = bb;
    }
    lcur[t] = excl;
    __syncthreads();
    bool staged = (n <= SSTAGE);
    for (int k = t; k < n; k += 256) {
        unsigned p = sedge[base + k];
        int dd = p & (NPB - 1);
        int pos = atomicAdd(&lcur[dd], 1);
        int svv = (int)(p >> NPB_BITS);
        if (staged) stage[pos] = svv;
        else        csr[base + pos] = svv;
    }
    __syncthreads();
    if (staged) {
        for (int k = t; k < n; k += 256) csr[base + k] = stage[k];
    }
}

// ---- layer-1 CSR gather: 8 lanes/node = (feature-half j, edge-quarter part) ----
#define ACC8(U)                                                         \
    l0 += BF_LO(U.x); h0 += BF_HI(U.x); l1 += BF_LO(U.y); h1 += BF_HI(U.y); \
    l2 += BF_LO(U.z); h2 += BF_HI(U.z); l3 += BF_LO(U.w); h3 += BF_HI(U.w);

__global__ __launch_bounds__(256) void k_agg1(const int* __restrict__ rowptr,
                                              const int* __restrict__ csr,
                                              const unsigned* __restrict__ g1,
                                              const float* __restrict__ dinv,
                                              const float* __restrict__ b1,
                                              const float* __restrict__ W2,
                                              float* __restrict__ g2, int N) {
    int gid = blockIdx.x * 256 + threadIdx.x;
    int i = gid >> 3;
    int j = gid & 1;                       // feature half (8 feats)
    int part = (gid >> 1) & 3;             // edge quarter
    if (i >= N) return;
    int e0 = rowptr[i], e1 = rowptr[i + 1];
    int len = e1 - e0;
    int qs = e0 + ((len * part) >> 2);
    int qe = e0 + ((len * (part + 1)) >> 2);
    const uint4* G = (const uint4*)g1;     // row i half j at G[i*2+j]
    float l0 = 0.f, h0 = 0.f, l1 = 0.f, h1 = 0.f;
    float l2 = 0.f, h2 = 0.f, l3 = 0.f, h3 = 0.f;
    if (part == 0) { uint4 w0 = G[i * 2 + j]; ACC8(w0) }   // self-loop once
    int e = qs;
    int p = (4 - (e & 3)) & 3;
    p = min(p, qe - e);
    for (int k = 0; k < p; ++k, ++e) { uint4 u = G[csr[e] * 2 + j]; ACC8(u) }
    const int4* c4 = (const int4*)(csr + e);
    int nq = (qe - e) >> 2;
    int q = 0;
    for (; q + 2 <= nq; q += 2) {
        int4 a = c4[q], b = c4[q + 1];
        uint4 u0 = G[a.x * 2 + j], u1 = G[a.y * 2 + j];
        uint4 u2 = G[a.z * 2 + j], u3 = G[a.w * 2 + j];
        uint4 u4 = G[b.x * 2 + j], u5 = G[b.y * 2 + j];
        uint4 u6 = G[b.z * 2 + j], u7 = G[b.w * 2 + j];
        ACC8(u0) ACC8(u1) ACC8(u2) ACC8(u3)
        ACC8(u4) ACC8(u5) ACC8(u6) ACC8(u7)
    }
    for (; q < nq; ++q) {
        int4 a = c4[q];
        uint4 u0 = G[a.x * 2 + j], u1 = G[a.y * 2 + j];
        uint4 u2 = G[a.z * 2 + j], u3 = G[a.w * 2 + j];
        ACC8(u0) ACC8(u1) ACC8(u2) ACC8(u3)
    }
    e += nq * 4;
    for (; e < qe; ++e) { uint4 u = G[csr[e] * 2 + j]; ACC8(u) }

    // reduce the 8 partial accums across parts (gid bits 1,2)
#pragma unroll
    for (int off = 2; off <= 4; off <<= 1) {
        l0 += __shfl_xor(l0, off, 8); h0 += __shfl_xor(h0, off, 8);
        l1 += __shfl_xor(l1, off, 8); h1 += __shfl_xor(h1, off, 8);
        l2 += __shfl_xor(l2, off, 8); h2 += __shfl_xor(h2, off, 8);
        l3 += __shfl_xor(l3, off, 8); h3 += __shfl_xor(h3, off, 8);
    }
    if (part != 0) return;
    float di = dinv[i];
    int fb = j * 8;
    float c0 = 0.f, c1 = 0.f;
#define EPI(val, fi)                                                     \
    {                                                                    \
        float v = fmaf((val), di, b1[fb + (fi)]);                        \
        v = v > 0.f ? v : 0.f;                                           \
        float2 w = ((const float2*)W2)[fb + (fi)];                       \
        c0 = fmaf(v, w.x, c0);                                           \
        c1 = fmaf(v, w.y, c1);                                           \
    }
    EPI(l0, 0) EPI(h0, 1) EPI(l1, 2) EPI(h1, 3)
    EPI(l2, 4) EPI(h2, 5) EPI(l3, 6) EPI(h3, 7)
    c0 += __shfl_xor(c0, 1, 2);
    c1 += __shfl_xor(c1, 1, 2);
    if (j == 0) ((float2*)g2)[i] = make_float2(c0 * di, c1 * di);
}

// ---- layer-2 CSR gather + fused log_softmax -> out (4 lanes/node) ----
__global__ __launch_bounds__(256) void k_agg2(const int* __restrict__ rowptr,
                                              const int* __restrict__ csr,
                                              const float* __restrict__ g2,
                                              const float* __restrict__ dinv,
                                              const float* __restrict__ b2,
                                              float* __restrict__ out, int N) {
    int gid = blockIdx.x * 256 + threadIdx.x;
    int i = gid >> 2;
    int l = gid & 3;
    if (i >= N) return;
    int e0 = rowptr[i], e1 = rowptr[i + 1];
    const float2* G2 = (const float2*)g2;
    float a0 = 0.f, a1 = 0.f;
    int e = e0 + l;
    for (; e + 4 < e1; e += 8) {
        int s0 = csr[e], s1 = csr[e + 4];
        float2 u = G2[s0];
        float2 w = G2[s1];
        a0 += u.x + w.x;
        a1 += u.y + w.y;
    }
    for (; e < e1; e += 4) {
        int s = csr[e];
        float2 u = G2[s];
        a0 += u.x;
        a1 += u.y;
    }
    a0 += __shfl_xor(a0, 1, 4); a0 += __shfl_xor(a0, 2, 4);
    a1 += __shfl_xor(a1, 1, 4); a1 += __shfl_xor(a1, 2, 4);
    if (l == 0) {
        float2 self = G2[i];
        float di = dinv[i];
        float A = fmaf(a0 + self.x, di, b2[0]);
        float B = fmaf(a1 + self.y, di, b2[1]);
        float m = fmaxf(A, B);
        float lse = m + logf(expf(A - m) + expf(B - m));
        ((float2*)out)[i] = make_float2(A - lse, B - lse);
    }
}

extern "C" void kernel_launch(void* const* d_in, const int* in_sizes, int n_in,
                              void* d_out, int out_size, void* d_ws, size_t ws_size,
                              hipStream_t stream) {
    const float* x  = (const float*)d_in[0];
    const int*   ei = (const int*)d_in[1];
    const float* W1 = (const float*)d_in[2];
    const float* b1 = (const float*)d_in[3];
    const float* W2 = (const float*)d_in[4];
    const float* b2 = (const float*)d_in[5];
    float* out = (float*)d_out;

    int N = in_sizes[0] / F_IN;
    int E = in_sizes[1] / 2;
    const int* src = ei;
    const int* dst = ei + E;
    int nbuck = (N + NPB - 1) >> NPB_BITS;
    int NB = (E + CHUNK - 1) / CHUNK;
    int NBg = (N * 4 + 255) / 256;

    int* cbM      = (int*)d_ws;                     // NB*MAXB (counts -> excl offsets)
    int* btot     = cbM + (long long)NB * MAXB;     // MAXB
    int* rowptr   = btot + MAXB;                    // N+1
    unsigned* sedge = (unsigned*)(rowptr + N + 1);  // E
    int* csr      = (int*)(sedge + E);              // E
    float* dinv   = (float*)(csr + E);              // N
    unsigned* g1  = (unsigned*)(dinv + N);          // 8N (bf16 rows)
    float* g2     = (float*)(g1 + (long long)8 * N);// 2N

    k_front<<<NBg + NB, 256, 0, stream>>>(x, W1, g1, N, dst, cbM, E, NBg);
    k_colscan<<<nbuck, 256, 0, stream>>>(cbM, btot, NB);
    k_binscatter<<<NB, 256, 0, stream>>>(src, dst, cbM, btot, sedge, E, nbuck);
    k_sortnode<<<nbuck, 256, 0, stream>>>(btot, sedge, csr, rowptr, dinv, g1, nbuck, N);

    k_agg1<<<((long long)N * 8 + 255) / 256, 256, 0, stream>>>(rowptr, csr, g1, dinv, b1, W2, g2, N);
    k_agg2<<<(N * 4 + 255) / 256, 256, 0, stream>>>(rowptr, csr, g2, dinv, b2, out, N);
}